// Round 15
// baseline (229.747 us; speedup 1.0000x reference)
//
#include <hip/hip_runtime.h>

#define NPAR 8
#define LPAR 16
#define OCH 128
#define HH 256
#define WW 256
#define HWSZ (HH*WW)

typedef _Float16 f16x8 __attribute__((ext_vector_type(8)));
typedef _Float16 f16x4 __attribute__((ext_vector_type(4)));
typedef _Float16 f16x2 __attribute__((ext_vector_type(2)));
typedef float    f32x4 __attribute__((ext_vector_type(4)));
typedef float    f32x16 __attribute__((ext_vector_type(16)));
typedef int      i32x4 __attribute__((ext_vector_type(4)));

// main kernel LDS: votes only, [128 rows][132]
#define SMEM_MAIN 16896
#define VROW 132
#define SMEM_HALVES_FUSED 16896

#if defined(__has_builtin)
#if __has_builtin(__builtin_amdgcn_fdot2)
#define HAVE_FDOT2 1
#endif
#if __has_builtin(__builtin_amdgcn_perm)
#define HAVE_PERM 1
#endif
#if __has_builtin(__builtin_amdgcn_ds_swizzle)
#define HAVE_DSSWZ 1
#endif
#endif

__device__ __forceinline__ float fdot2_acc(f16x2 a, f16x2 b, float c) {
#ifdef HAVE_FDOT2
    return __builtin_amdgcn_fdot2(a, b, c, false);   // v_dot2_f32_f16
#else
    return c + (float)a[0] * (float)b[0] + (float)a[1] * (float)b[1];
#endif
}

// packed quad-sum via DPP (VALU-only; used by fallback kernel)
__device__ __forceinline__ f16x2 quad_sum4_pk(f16x2 v) {
    int t = __builtin_amdgcn_update_dpp(0, __builtin_bit_cast(int, v),
                                        0xB1, 0xF, 0xF, true);   // [1,0,3,2]
    v = v + __builtin_bit_cast(f16x2, t);
    t = __builtin_amdgcn_update_dpp(0, __builtin_bit_cast(int, v),
                                    0x4E, 0xF, 0xF, true);       // [2,3,0,1]
    v = v + __builtin_bit_cast(f16x2, t);
    return v;
}

// packed quad-sum via ds_swizzle: lane exchange runs on the (idle) LDS
// crossbar pipe instead of VALU -> frees 2 VALU issue slots per call.
// BitMode offset = (xor<<10)|(or<<5)|and: xor1 = 0x041F, xor2 = 0x081F.
__device__ __forceinline__ f16x2 quad_sum4_ds(f16x2 v) {
#ifdef HAVE_DSSWZ
    int t = __builtin_amdgcn_ds_swizzle(__builtin_bit_cast(int, v), 0x041F);
    v = v + __builtin_bit_cast(f16x2, t);
    t = __builtin_amdgcn_ds_swizzle(__builtin_bit_cast(int, v), 0x081F);
    v = v + __builtin_bit_cast(f16x2, t);
    return v;
#else
    return quad_sum4_pk(v);
#endif
}

// ---- pre-pass: W (f32 [128 oc][16 ci][25 tap]) -> wsB fp16 [25 tap][128 oc][16 ci]
__global__ void reorder_W25(const float* __restrict__ Wg,
                            _Float16* __restrict__ ws) {
    int idx = blockIdx.x * 256 + threadIdx.x;
    if (idx >= 25 * 128 * 16) return;
    const int ci  = idx & 15;
    const int oc  = (idx >> 4) & 127;
    const int tap = idx >> 11;
    ws[idx] = (_Float16)Wg[oc * 400 + ci * 25 + tap];
}

// ---- pre-pass: W reorder, linear 13-kk layout (fallback kernel) ----
__global__ void reorder_W_lin(const float* __restrict__ Wg,
                              _Float16* __restrict__ ws) {
    int idx = blockIdx.x * 256 + threadIdx.x;
    if (idx >= 13 * 128 * 32) return;
    const int q  = idx & 31;
    const int oc = (idx >> 5) & 127;
    const int kk = idx >> 12;
    const int tap = 2 * kk + (q >> 4);
    const int ci  = ((q >> 3) & 1) * 8 + (q & 7);
    const float v = (tap < 25) ? Wg[oc * 400 + ci * 25 + tap] : 0.f;
    ws[idx] = (_Float16)v;
}

// ---- pre-pass: x (f32 NCHW) -> xh fp16 NHWC padded [4][260][260][64] ----
__global__ __launch_bounds__(256)
void transpose_x_kernel(const float* __restrict__ x, _Float16* __restrict__ xh) {
    __shared__ _Float16 ts[4096];      // [64 w][8 granules][8 ch]
    const int tid = threadIdx.x;
    const int bx  = blockIdx.x;
    const int b   = bx >> 10;
    const int h   = (bx >> 2) & 255;
    const int wt  = bx & 3;
    const int w0  = wt * 64;
    {
        const int wl = tid & 63, cq = tid >> 6;      // 16 channels per thread
        const float* src = x + (((size_t)(b * 64 + cq * 16) * 256 + h) * 256 + w0 + wl);
#pragma unroll
        for (int k = 0; k < 2; ++k) {
            f16x8 pk;
#pragma unroll
            for (int j = 0; j < 8; ++j)
                pk[j] = (_Float16)src[(size_t)(k * 8 + j) * HWSZ];
            const int gL = (cq * 2 + k) ^ (wl & 7);  // bank-spread store
            *(f16x8*)&ts[wl * 64 + gL * 8] = pk;
        }
    }
    __syncthreads();
    {
        const int wo = tid >> 2, gq = tid & 3;
        _Float16* dst = xh + (((size_t)(b * 260) + h + 2) * 260 + (w0 + wo + 2)) * 64 + gq * 16;
#pragma unroll
        for (int k = 0; k < 2; ++k) {
            const int gL = (gq * 2 + k) ^ (wo & 7);
            *(f16x8*)&dst[k * 8] = *(const f16x8*)&ts[wo * 64 + gL * 8];
        }
    }
}

// ===================== MAIN: 32x32x16 MFMA conv + DS-offloaded routing ==========
// Identical to round-14 structure; only quad-sum moved to the DS pipe.
__global__ __launch_bounds__(256, 3)
void capsule_mfma12_kernel(const _Float16* __restrict__ xh,
                           const _Float16* __restrict__ wsB,
                           float* __restrict__ out) {
    __shared__ _Float16 sm[SMEM_MAIN];

    const int tid = threadIdx.x;
    const int w   = tid >> 6;
    const int l   = tid & 63;

    // XCD-aware swizzle (8192 = 8*1024, bijective)
    const int blk   = ((blockIdx.x & 7) << 10) + (blockIdx.x >> 3);
    const int b     = blk >> 11;
    const int rt    = blk & 2047;
    const int hrow0 = (rt >> 4) << 1;
    const int w0    = (rt & 15) << 4;

    const int rwc = w >> 1;            // wave's image row (0/1)
    const int oh  = w & 1;             // wave's oc-half
    const int l31 = l & 31;
    const int kh  = l >> 5;            // k-half: ci in [kh*8, kh*8+8)
    const int ncA = l31 & 3;
    const int pxq = l31 >> 2;

    // af base pointers, one per dy (padded xh)
    const _Float16* gb = xh + (((size_t)(b * 260 + hrow0 + rwc)) * 260 + w0 + pxq) * 64
                       + ncA * 16 + kh * 8;
    const _Float16* bP[5] = { gb, gb + 16640, gb + 2 * 16640, gb + 3 * 16640, gb + 4 * 16640 };

    // bf per-lane base: wsB[tap][oc = oh*64 + nt*32 + l31][ci = kh*8 ..]
    const _Float16* wbase = wsB + (oh * 64 + l31) * 16 + kh * 8;

    f32x16 acc[2][2];
#pragma unroll
    for (int mt = 0; mt < 2; ++mt)
#pragma unroll
        for (int nt = 0; nt < 2; ++nt)
#pragma unroll
            for (int r = 0; r < 16; ++r)
                acc[mt][nt][r] = 0.f;

#pragma unroll
    for (int tap = 0; tap < 25; ++tap) {
        const int dy = tap / 5;        // compile-time (unrolled)
        const int dx = tap % 5;
        const f16x8 bf0 = *(const f16x8*)(wbase + tap * 2048);
        const f16x8 bf1 = *(const f16x8*)(wbase + tap * 2048 + 512);
        const f16x8 af0 = *(const f16x8*)(bP[dy] + (size_t)(dx)      * 64);
        const f16x8 af1 = *(const f16x8*)(bP[dy] + (size_t)(dx + 8)  * 64);
        __builtin_amdgcn_s_setprio(1);
        acc[0][0] = __builtin_amdgcn_mfma_f32_32x32x16_f16(af0, bf0, acc[0][0], 0, 0, 0);
        acc[0][1] = __builtin_amdgcn_mfma_f32_32x32x16_f16(af0, bf1, acc[0][1], 0, 0, 0);
        acc[1][0] = __builtin_amdgcn_mfma_f32_32x32x16_f16(af1, bf0, acc[1][0], 0, 0, 0);
        acc[1][1] = __builtin_amdgcn_mfma_f32_32x32x16_f16(af1, bf1, acc[1][1], 0, 0, 0);
        __builtin_amdgcn_s_setprio(0);
    }

    // ---- epilogue: acc -> votes LDS fp16. Slot layout: col = lp*8 + slot,
    // slot = oh*4 + hi*2 + nt (hi = l31>>4). np = oh*4 + nt*2 + hi (remapped at output).
#pragma unroll
    for (int mt = 0; mt < 2; ++mt) {
#pragma unroll
        for (int reg = 0; reg < 16; ++reg) {
            const f16x2 pk = (f16x2){(_Float16)acc[mt][0][reg], (_Float16)acc[mt][1][reg]};
            const int pxt = mt * 8 + 2 * (reg >> 2) + kh;   // px in tile
            const int R   = rwc * 64 + pxt * 4 + (reg & 3); // row*4 + nc
            *(f16x2*)&sm[R * VROW + (l & 15) * 8 + oh * 4 + ((l31 >> 4) << 1)] = pk;
        }
    }
    __syncthreads();

    // ---- routing (r13/r14-verified structure; quad-sum on DS pipe) ----
    const int ncR = tid & 3;
    const int h   = (tid >> 2) & 1;
    const int pxx = (tid >> 3) & 15;
    const int rw  = tid >> 7;

    const int R = rw * 64 + pxx * 4 + ncR;
    f16x8 vh[8];
#pragma unroll
    for (int c8 = 0; c8 < 8; ++c8)
        vh[c8] = *(const f16x8*)&sm[R * VROW + (h * 8 + c8) * 8];

    // hoisted transpose: vnpw[slot][K] = f16x2(vh[2K][slot], vh[2K+1][slot])
    int vnpw[NPAR][4];
#pragma unroll
    for (int K = 0; K < 4; ++K) {
        const i32x4 A = __builtin_bit_cast(i32x4, vh[2 * K]);
        const i32x4 B = __builtin_bit_cast(i32x4, vh[2 * K + 1]);
#pragma unroll
        for (int nh = 0; nh < 4; ++nh) {
#ifdef HAVE_PERM
            vnpw[2 * nh][K]     = (int)__builtin_amdgcn_perm(
                (unsigned)B[nh], (unsigned)A[nh], 0x05040100u);
            vnpw[2 * nh + 1][K] = (int)__builtin_amdgcn_perm(
                (unsigned)B[nh], (unsigned)A[nh], 0x07060302u);
#else
            const f16x2 lo = (f16x2){vh[2 * K][2 * nh],     vh[2 * K + 1][2 * nh]};
            const f16x2 hi = (f16x2){vh[2 * K][2 * nh + 1], vh[2 * K + 1][2 * nh + 1]};
            vnpw[2 * nh][K]     = __builtin_bit_cast(int, lo);
            vnpw[2 * nh + 1][K] = __builtin_bit_cast(int, hi);
#endif
        }
    }

    float* outb = out + (size_t)b * OCH * HWSZ
                + (size_t)(hrow0 + rw) * WW + (w0 + pxx);

    float sims[NPAR];
#pragma unroll
    for (int i = 0; i < NPAR; ++i) sims[i] = 0.f;

#pragma unroll
    for (int it = 0; it < 3; ++it) {
        float e[NPAR];
        float inv = 0.f;
        if (it > 0) {                  // it==0: softmax(0) exactly uniform
            float mx = fmaxf(fmaxf(fmaxf(sims[0], sims[1]), fmaxf(sims[2], sims[3])),
                             fmaxf(fmaxf(sims[4], sims[5]), fmaxf(sims[6], sims[7])));
            float se = 0.f;
#pragma unroll
            for (int i = 0; i < NPAR; ++i) { e[i] = __expf(sims[i] - mx); se += e[i]; }
            inv = 1.f / se;
        }
#pragma unroll
        for (int s = 0; s < NPAR; ++s) {           // s = slot index
            const float cf = (it == 0) ? 0.f : e[s] * inv;
            const f16x2 cp = (f16x2){(_Float16)cf, (_Float16)cf};
            float n2 = 0.f, dot = 0.f;
            f16x2 keep0 = (f16x2){(_Float16)0.f, (_Float16)0.f};
            f16x2 keep1 = keep0;
#pragma unroll
            for (int K = 0; K < 4; ++K) {
                const f16x2 vv = __builtin_bit_cast(f16x2, vnpw[s][K]);
                const f16x2 sv = (it == 0) ? vv : (cp * vv);   // it0: fold 1/8 later
                const f16x2 t2 = quad_sum4_ds(sv);             // DS-pipe exchange
                n2 = fdot2_acc(t2, t2, n2);
                if (it < 2) dot = fdot2_acc(vv, t2, dot);
                if (it == 2 && (K >> 1) == (ncR & 1)) {
                    if (K & 1) keep1 = t2; else keep0 = t2;
                }
            }
            n2 += __shfl_xor(n2, 4);
            if (it == 0) n2 *= 0.015625f;          // (1/8)^2, exact
            const float scale = sqrtf(n2) / (1.f + n2 + 1e-4f);
            if (it < 2) {
                dot += __shfl_xor(dot, 4);
                if (it == 0) dot *= 0.125f;        // 1/8, exact
                sims[s] += scale * dot;
            }
            if (it == 2 && (ncR >> 1) == h) {
                // slot -> np remap (compile-time per unrolled s)
                const int np_out = (s & 4) | ((s & 1) << 1) | ((s >> 1) & 1);
                outb[(size_t)(np_out * LPAR + ncR * 4 + 0) * HWSZ] = scale * (float)keep0[0];
                outb[(size_t)(np_out * LPAR + ncR * 4 + 1) * HWSZ] = scale * (float)keep0[1];
                outb[(size_t)(np_out * LPAR + ncR * 4 + 2) * HWSZ] = scale * (float)keep1[0];
                outb[(size_t)(np_out * LPAR + ncR * 4 + 3) * HWSZ] = scale * (float)keep1[1];
            }
        }
    }
}

// ===================== FALLBACK: round-8 kernel (ws too small) =====================
__device__ __forceinline__ int xs_addr6(int dyr, int wp, int col) {
    return (dyr * 20 + wp) * 64 + (col ^ ((wp & 7) << 3));
}

__global__ __launch_bounds__(256, 3)
void capsule_mfma6_kernel(const float* __restrict__ x,
                          const _Float16* __restrict__ wsf,
                          float* __restrict__ out) {
    __shared__ _Float16 sm[SMEM_HALVES_FUSED];

    const int tid = threadIdx.x;
    const int w   = tid >> 6;
    const int l   = tid & 63;

    const int blk   = ((blockIdx.x & 7) << 10) + (blockIdx.x >> 3);
    const int b     = blk >> 11;
    const int rt    = blk & 2047;
    const int hrow0 = (rt >> 4) << 1;
    const int w0    = (rt & 15) << 4;

    for (int i = 0; i < 15; ++i) {
        const unsigned idx = i * 256 + tid;
        const unsigned q   = idx / 20u;
        const int wp  = idx - q * 20u;
        const int cip = q & 7;
        const int t2  = q >> 3;
        const int nc  = t2 & 3;
        const int dyr = t2 >> 2;
        const int hh  = hrow0 + dyr - 2;
        const int wg  = w0 + wp - 2;
        const bool ok = (hh >= 0) && (hh < HH) && (wg >= 0) && (wg < WW);
        const float* src = x + (((size_t)(b * 4 + nc) * 16 + cip * 2) * HH + hh) * (size_t)WW + wg;
        const float v0 = ok ? src[0] : 0.f;
        const float v1 = ok ? src[HWSZ] : 0.f;
        *(f16x2*)&sm[xs_addr6(dyr, wp, nc * 16 + cip * 2)] =
            (f16x2){(_Float16)v0, (_Float16)v1};
    }
    __syncthreads();

    const int rwc = w >> 1;
    const int oh  = w & 1;
    const int p   = l >> 4;
    const int ml  = l & 15;
    const bool hiT = (p & 2) != 0;
    const int ciA = (p & 1) * 8;
    const int pxA = ml >> 2;
    const int ncA = ml & 3;
    const int bfbase = (oh * 64 + ml) * 32 + p * 8;

    f32x4 acc[4][4];
#pragma unroll
    for (int a = 0; a < 4; ++a)
#pragma unroll
        for (int bb = 0; bb < 4; ++bb)
            acc[a][bb] = (f32x4){0.f, 0.f, 0.f, 0.f};

#pragma unroll
    for (int kk = 0; kk < 13; ++kk) {
        f16x8 bf[4];
#pragma unroll
        for (int bb = 0; bb < 4; ++bb)
            bf[bb] = *(const f16x8*)&wsf[kk * 4096 + bb * 512 + bfbase];

        const int t0 = 2 * kk;
        const int t1 = (2 * kk + 1 > 24) ? 24 : 2 * kk + 1;
        const int dy = hiT ? (t1 / 5) : (t0 / 5);
        const int dx = hiT ? (t1 % 5) : (t0 % 5);

        f16x8 af[4];
#pragma unroll
        for (int a = 0; a < 4; ++a)
            af[a] = *(const f16x8*)&sm[xs_addr6(rwc + dy, a * 4 + pxA + dx, ncA * 16 + ciA)];

#pragma unroll
        for (int a = 0; a < 4; ++a)
#pragma unroll
            for (int bb = 0; bb < 4; ++bb)
                acc[a][bb] = __builtin_amdgcn_mfma_f32_16x16x32_f16(
                    af[a], bf[bb], acc[a][bb], 0, 0, 0);
    }
    __syncthreads();

#pragma unroll
    for (int a = 0; a < 4; ++a) {
#pragma unroll
        for (int reg = 0; reg < 4; ++reg) {
            f16x4 pk;
#pragma unroll
            for (int bb = 0; bb < 4; ++bb) pk[bb] = (_Float16)acc[a][bb][reg];
            const int R = rwc * 64 + a * 16 + p * 4 + reg;
            *(f16x4*)&sm[R * VROW + ml * 8 + oh * 4] = pk;
        }
    }
    __syncthreads();

    const int ncR = tid & 3;
    const int h   = (tid >> 2) & 1;
    const int pxx = (tid >> 3) & 15;
    const int rw  = tid >> 7;

    const int R = rw * 64 + pxx * 4 + ncR;
    f16x8 vh[8];
#pragma unroll
    for (int c8 = 0; c8 < 8; ++c8)
        vh[c8] = *(const f16x8*)&sm[R * VROW + (h * 8 + c8) * 8];

    float* outb = out + (size_t)b * OCH * HWSZ
                + (size_t)(hrow0 + rw) * WW + (w0 + pxx);

    float sims[NPAR];
#pragma unroll
    for (int i = 0; i < NPAR; ++i) sims[i] = 0.f;

#pragma unroll
    for (int it = 0; it < 3; ++it) {
        float mx = fmaxf(fmaxf(fmaxf(sims[0], sims[1]), fmaxf(sims[2], sims[3])),
                         fmaxf(fmaxf(sims[4], sims[5]), fmaxf(sims[6], sims[7])));
        float e[NPAR];
        float se = 0.f;
#pragma unroll
        for (int i = 0; i < NPAR; ++i) { e[i] = __expf(sims[i] - mx); se += e[i]; }
        const float inv = 1.f / se;

#pragma unroll
        for (int np_ = 0; np_ < NPAR; ++np_) {
            const float cf = e[np_] * inv;
            const f16x2 cp = (f16x2){(_Float16)cf, (_Float16)cf};
            float n2 = 0.f, dot = 0.f;
            f16x2 keep0 = (f16x2){(_Float16)0.f, (_Float16)0.f};
            f16x2 keep1 = keep0;
#pragma unroll
            for (int k = 0; k < 4; ++k) {
                const f16x2 vv = (f16x2){vh[2 * k][np_], vh[2 * k + 1][np_]};
                const f16x2 t2 = quad_sum4_pk(cp * vv);
                n2  = fdot2_acc(t2, t2, n2);
                dot = fdot2_acc(vv, t2, dot);
                if (it == 2 && (k >> 1) == (ncR & 1)) {
                    if (k & 1) keep1 = t2; else keep0 = t2;
                }
            }
            n2  += __shfl_xor(n2, 4);
            dot += __shfl_xor(dot, 4);
            const float scale = sqrtf(n2) / (1.f + n2 + 1e-4f);
            sims[np_] += scale * dot;

            if (it == 2 && (ncR >> 1) == h) {
                outb[(size_t)(np_ * LPAR + ncR * 4 + 0) * HWSZ] = scale * (float)keep0[0];
                outb[(size_t)(np_ * LPAR + ncR * 4 + 1) * HWSZ] = scale * (float)keep0[1];
                outb[(size_t)(np_ * LPAR + ncR * 4 + 2) * HWSZ] = scale * (float)keep1[0];
                outb[(size_t)(np_ * LPAR + ncR * 4 + 3) * HWSZ] = scale * (float)keep1[1];
            }
        }
    }
}

extern "C" void kernel_launch(void* const* d_in, const int* in_sizes, int n_in,
                              void* d_out, int out_size, void* d_ws, size_t ws_size,
                              hipStream_t stream) {
    const float* x  = (const float*)d_in[0];   // (4,4,16,256,256) f32
    const float* Wg = (const float*)d_in[1];   // (128,16,5,5) f32
    float* out = (float*)d_out;                // (4,8,16,256,256) f32
    _Float16* ws = (_Float16*)d_ws;
    (void)in_sizes; (void)n_in; (void)out_size;

    const size_t XH_BYTES = (size_t)4 * 260 * 260 * 64 * 2;   // 34,611,200
    const size_t NEED = 131072 + XH_BYTES;

    if (ws_size >= NEED) {
        _Float16* xh = ws + 65536;   // byte offset 131072 (wsB uses 102,400 B)
        hipLaunchKernelGGL(reorder_W25, dim3(200), dim3(256), 0, stream, Wg, ws);
        hipMemsetAsync((void*)xh, 0, XH_BYTES, stream);
        hipLaunchKernelGGL(transpose_x_kernel, dim3(4096), dim3(256), 0, stream, x, xh);
        hipLaunchKernelGGL(capsule_mfma12_kernel, dim3(8192), dim3(256), 0, stream,
                           xh, ws, out);
    } else {
        hipLaunchKernelGGL(reorder_W_lin, dim3(208), dim3(256), 0, stream, Wg, ws);
        hipLaunchKernelGGL(capsule_mfma6_kernel, dim3(8192), dim3(256), 0, stream,
                           x, ws, out);
    }
}

// Round 16
// 219.117 us; speedup vs baseline: 1.0485x; 1.0485x over previous
//
#include <hip/hip_runtime.h>

#define NPAR 8
#define LPAR 16
#define OCH 128
#define HH 256
#define WW 256
#define HWSZ (HH*WW)

typedef _Float16 f16x8 __attribute__((ext_vector_type(8)));
typedef _Float16 f16x4 __attribute__((ext_vector_type(4)));
typedef _Float16 f16x2 __attribute__((ext_vector_type(2)));
typedef float    f32x4 __attribute__((ext_vector_type(4)));

// ---- main-kernel LDS map (halves) ----
//   xs [0, 7680)  (conv phase)   |   votes [0, 16896) (epilogue union)
#define SMEM_MAIN 16896
#define VROW 132
#define SMEM_HALVES_FUSED 16896

#if defined(__has_builtin)
#if __has_builtin(__builtin_amdgcn_fdot2)
#define HAVE_FDOT2 1
#endif
#if __has_builtin(__builtin_amdgcn_global_load_lds)
#define HAVE_GLL 1
#endif
#endif

__device__ __forceinline__ float fdot2_acc(f16x2 a, f16x2 b, float c) {
#ifdef HAVE_FDOT2
    return __builtin_amdgcn_fdot2(a, b, c, false);   // v_dot2_f32_f16
#else
    return c + (float)a[0] * (float)b[0] + (float)a[1] * (float)b[1];
#endif
}

// packed quad-sum: DPP quad_perm on the b32 container -> both f16 halves
__device__ __forceinline__ f16x2 quad_sum4_pk(f16x2 v) {
    int t = __builtin_amdgcn_update_dpp(0, __builtin_bit_cast(int, v),
                                        0xB1, 0xF, 0xF, true);   // [1,0,3,2]
    v = v + __builtin_bit_cast(f16x2, t);
    t = __builtin_amdgcn_update_dpp(0, __builtin_bit_cast(int, v),
                                    0x4E, 0xF, 0xF, true);       // [2,3,0,1]
    v = v + __builtin_bit_cast(f16x2, t);
    return v;
}

// DMA 16B/lane: gp per-lane, lp wave-uniform (HW adds lane*16)
__device__ __forceinline__ void stage16(const _Float16* gp, _Float16* lp, int lane) {
#ifdef HAVE_GLL
    __builtin_amdgcn_global_load_lds((const __attribute__((address_space(1))) void*)gp,
                                     (__attribute__((address_space(3))) void*)lp, 16, 0, 0);
#else
    *(f16x8*)(lp + lane * 8) = *(const f16x8*)gp;
#endif
}

// ---- pre-pass: W reorder, linear B-fragment layout ----
// ws[kk][oc][q], q = kq*8+j: tap = 2kk+(kq>>1), ci = (kq&1)*8 + j
__global__ void reorder_W_lin(const float* __restrict__ Wg,
                              _Float16* __restrict__ ws) {
    int idx = blockIdx.x * 256 + threadIdx.x;
    if (idx >= 13 * 128 * 32) return;
    const int q  = idx & 31;
    const int oc = (idx >> 5) & 127;
    const int kk = idx >> 12;
    const int tap = 2 * kk + (q >> 4);
    const int ci  = ((q >> 3) & 1) * 8 + (q & 7);
    const float v = (tap < 25) ? Wg[oc * 400 + ci * 25 + tap] : 0.f;
    ws[idx] = (_Float16)v;
}

// ---- pre-pass: x (f32 NCHW) -> xh fp16 NHWC padded [4][260][260][64] ----
__global__ __launch_bounds__(256)
void transpose_x_kernel(const float* __restrict__ x, _Float16* __restrict__ xh) {
    __shared__ _Float16 ts[4096];      // [64 w][8 granules][8 ch]
    const int tid = threadIdx.x;
    const int bx  = blockIdx.x;
    const int b   = bx >> 10;
    const int h   = (bx >> 2) & 255;
    const int wt  = bx & 3;
    const int w0  = wt * 64;
    {
        const int wl = tid & 63, cq = tid >> 6;      // 16 channels per thread
        const float* src = x + (((size_t)(b * 64 + cq * 16) * 256 + h) * 256 + w0 + wl);
#pragma unroll
        for (int k = 0; k < 2; ++k) {
            f16x8 pk;
#pragma unroll
            for (int j = 0; j < 8; ++j)
                pk[j] = (_Float16)src[(size_t)(k * 8 + j) * HWSZ];
            const int gL = (cq * 2 + k) ^ (wl & 7);  // bank-spread store
            *(f16x8*)&ts[wl * 64 + gL * 8] = pk;
        }
    }
    __syncthreads();
    {
        const int wo = tid >> 2, gq = tid & 3;
        _Float16* dst = xh + (((size_t)(b * 260) + h + 2) * 260 + (w0 + wo + 2)) * 64 + gq * 16;
#pragma unroll
        for (int k = 0; k < 2; ++k) {
            const int gL = (gq * 2 + k) ^ (wo & 7);
            *(f16x8*)&dst[k * 8] = *(const f16x8*)&ts[wo * 64 + gL * 8];
        }
    }
}

// ===================== MAIN: barrier-free conv K-loop + fused routing ==========
// 8192 blocks, tile 2 rows x 16 px. 4 waves: rwc=w>>1 (row), oh=w&1 (oc half).
// xs DMA'd (granule-preswizzled source, linear LDS dest); W fragments read
// DIRECTLY from global (L2-hot 106 KB shared chip-wide) -> no per-phase
// barriers; compiler pipelines bf loads across the unrolled 13-kk loop.
__global__ __launch_bounds__(256, 3)
void capsule_mfma10_kernel(const _Float16* __restrict__ xh,
                           const _Float16* __restrict__ wsW,
                           float* __restrict__ out) {
    __shared__ _Float16 sm[SMEM_MAIN];

    const int tid = threadIdx.x;
    const int w   = tid >> 6;
    const int l   = tid & 63;

    // XCD-aware swizzle (8192 = 8*1024, bijective)
    const int blk   = ((blockIdx.x & 7) << 10) + (blockIdx.x >> 3);
    const int b     = blk >> 11;
    const int rt    = blk & 2047;
    const int hrow0 = (rt >> 4) << 1;
    const int w0    = (rt & 15) << 4;

    // ---- stage xs: 15 DMA calls; LDS linear, source granule pre-swizzled ----
    {
        const size_t bbase = ((size_t)(b * 260 + hrow0) * 260 + w0) * 64;
#pragma unroll
        for (int jj = 0; jj < 4; ++jj) {
            const int cidx = w * 4 + jj;
            if (cidx < 15) {
                const int G = cidx * 64 + l;
                const unsigned dyr = (unsigned)G / 160u;
                const unsigned rem = (unsigned)G - dyr * 160u;
                const int wp = rem >> 3, g = rem & 7;
                const int gsrc = g ^ (wp & 7);
                const _Float16* gp = xh + bbase + dyr * 16640u + wp * 64 + gsrc * 8;
                stage16(gp, &sm[cidx * 512], l);
            }
        }
    }
    __syncthreads();

    const int rwc = w >> 1;
    const int oh  = w & 1;
    const int kq  = l >> 4;
    const int ml  = l & 15;
    const bool hiT = (kq & 2) != 0;
    const int pxA = ml >> 2;
    const int colA = (ml & 3) * 16 + (kq & 1) * 8;   // ncA*16 + ciA
    const int bfbase = (oh * 64 + ml) * 32 + kq * 8;

    f32x4 acc[4][4];
#pragma unroll
    for (int a = 0; a < 4; ++a)
#pragma unroll
        for (int bb = 0; bb < 4; ++bb)
            acc[a][bb] = (f32x4){0.f, 0.f, 0.f, 0.f};

#pragma unroll
    for (int kk = 0; kk < 13; ++kk) {
        // B frags direct from global (L2-hot); compiler pipelines across kk
        f16x8 bf[4];
#pragma unroll
        for (int bb = 0; bb < 4; ++bb)
            bf[bb] = *(const f16x8*)&wsW[kk * 4096 + bb * 512 + bfbase];

        // compile-time dy/dx pairs, one cndmask each
        const int t0 = 2 * kk;
        const int t1 = (2 * kk + 1 > 24) ? 24 : 2 * kk + 1;
        const int dy = hiT ? (t1 / 5) : (t0 / 5);
        const int dx = hiT ? (t1 % 5) : (t0 % 5);

        f16x8 af[4];
#pragma unroll
        for (int a = 0; a < 4; ++a) {
            const int wp = a * 4 + pxA + dx;
            af[a] = *(const f16x8*)&sm[((rwc + dy) * 20 + wp) * 64
                                       + (colA ^ ((wp & 7) << 3))];
        }
        __builtin_amdgcn_s_setprio(1);
#pragma unroll
        for (int a = 0; a < 4; ++a)
#pragma unroll
            for (int bb = 0; bb < 4; ++bb)
                acc[a][bb] = __builtin_amdgcn_mfma_f32_16x16x32_f16(
                    af[a], bf[bb], acc[a][bb], 0, 0, 0);
        __builtin_amdgcn_s_setprio(0);
    }
    __syncthreads();   // xs region about to be overwritten by votes

    // ---- epilogue: acc -> votes LDS fp16 (col = lp*8 + np, np = oh*4+bb) ----
#pragma unroll
    for (int a = 0; a < 4; ++a) {
#pragma unroll
        for (int reg = 0; reg < 4; ++reg) {
            f16x4 pk;
#pragma unroll
            for (int bb = 0; bb < 4; ++bb) pk[bb] = (_Float16)acc[a][bb][reg];
            const int R = rwc * 64 + a * 16 + kq * 4 + reg;
            *(f16x4*)&sm[R * VROW + ml * 8 + oh * 4] = pk;
        }
    }
    __syncthreads();

    // ---- routing: thread = (rw, px, h, nc); lp halves split over h ----
    const int ncR = tid & 3;
    const int h   = (tid >> 2) & 1;
    const int pxx = (tid >> 3) & 15;
    const int rw  = tid >> 7;

    const int R = rw * 64 + pxx * 4 + ncR;
    f16x8 vh[8];
#pragma unroll
    for (int c8 = 0; c8 < 8; ++c8)
        vh[c8] = *(const f16x8*)&sm[R * VROW + (h * 8 + c8) * 8];

    float* outb = out + (size_t)b * OCH * HWSZ
                + (size_t)(hrow0 + rw) * WW + (w0 + pxx);

    float sims[NPAR];
#pragma unroll
    for (int i = 0; i < NPAR; ++i) sims[i] = 0.f;

#pragma unroll
    for (int it = 0; it < 3; ++it) {
        float e[NPAR];
        float inv = 0.f;
        if (it > 0) {                  // it==0: softmax(0) exactly uniform
            float mx = fmaxf(fmaxf(fmaxf(sims[0], sims[1]), fmaxf(sims[2], sims[3])),
                             fmaxf(fmaxf(sims[4], sims[5]), fmaxf(sims[6], sims[7])));
            float se = 0.f;
#pragma unroll
            for (int i = 0; i < NPAR; ++i) { e[i] = __expf(sims[i] - mx); se += e[i]; }
            inv = 1.f / se;
        }
#pragma unroll
        for (int np_ = 0; np_ < NPAR; ++np_) {
            const float cf = (it == 0) ? 0.f : e[np_] * inv;
            const f16x2 cp = (f16x2){(_Float16)cf, (_Float16)cf};
            float n2 = 0.f, dot = 0.f;
            f16x2 keep0 = (f16x2){(_Float16)0.f, (_Float16)0.f};
            f16x2 keep1 = keep0;
#pragma unroll
            for (int k = 0; k < 4; ++k) {
                const f16x2 vv = (f16x2){vh[2 * k][np_], vh[2 * k + 1][np_]};
                // it0: c = 1/8 exactly -> fold power-of-2 scale after reduce
                const f16x2 sv = (it == 0) ? vv : (cp * vv);
                const f16x2 t2 = quad_sum4_pk(sv);
                n2 = fdot2_acc(t2, t2, n2);
                if (it < 2) dot = fdot2_acc(vv, t2, dot);
                if (it == 2 && (k >> 1) == (ncR & 1)) {
                    if (k & 1) keep1 = t2; else keep0 = t2;
                }
            }
            n2 += __shfl_xor(n2, 4);
            if (it == 0) n2 *= 0.015625f;          // (1/8)^2, exact
            const float scale = sqrtf(n2) / (1.f + n2 + 1e-4f);
            if (it < 2) {
                dot += __shfl_xor(dot, 4);
                if (it == 0) dot *= 0.125f;        // 1/8, exact
                sims[np_] += scale * dot;
            }
            if (it == 2 && (ncR >> 1) == h) {
                outb[(size_t)(np_ * LPAR + ncR * 4 + 0) * HWSZ] = scale * (float)keep0[0];
                outb[(size_t)(np_ * LPAR + ncR * 4 + 1) * HWSZ] = scale * (float)keep0[1];
                outb[(size_t)(np_ * LPAR + ncR * 4 + 2) * HWSZ] = scale * (float)keep1[0];
                outb[(size_t)(np_ * LPAR + ncR * 4 + 3) * HWSZ] = scale * (float)keep1[1];
            }
        }
    }
}

// ===================== FALLBACK: exact round-8 kernel =====================
__device__ __forceinline__ int xs_addr6(int dyr, int wp, int col) {
    return (dyr * 20 + wp) * 64 + (col ^ ((wp & 7) << 3));
}

__global__ __launch_bounds__(256, 3)
void capsule_mfma6_kernel(const float* __restrict__ x,
                          const _Float16* __restrict__ wsf,
                          float* __restrict__ out) {
    __shared__ _Float16 sm[SMEM_HALVES_FUSED];

    const int tid = threadIdx.x;
    const int w   = tid >> 6;
    const int l   = tid & 63;

    const int blk   = ((blockIdx.x & 7) << 10) + (blockIdx.x >> 3);
    const int b     = blk >> 11;
    const int rt    = blk & 2047;
    const int hrow0 = (rt >> 4) << 1;
    const int w0    = (rt & 15) << 4;

    for (int i = 0; i < 15; ++i) {
        const unsigned idx = i * 256 + tid;
        const unsigned q   = idx / 20u;
        const int wp  = idx - q * 20u;
        const int cip = q & 7;
        const int t2  = q >> 3;
        const int nc  = t2 & 3;
        const int dyr = t2 >> 2;
        const int hh  = hrow0 + dyr - 2;
        const int wg  = w0 + wp - 2;
        const bool ok = (hh >= 0) && (hh < HH) && (wg >= 0) && (wg < WW);
        const float* src = x + (((size_t)(b * 4 + nc) * 16 + cip * 2) * HH + hh) * (size_t)WW + wg;
        const float v0 = ok ? src[0] : 0.f;
        const float v1 = ok ? src[HWSZ] : 0.f;
        *(f16x2*)&sm[xs_addr6(dyr, wp, nc * 16 + cip * 2)] =
            (f16x2){(_Float16)v0, (_Float16)v1};
    }
    __syncthreads();

    const int rwc = w >> 1;
    const int oh  = w & 1;
    const int p   = l >> 4;
    const int ml  = l & 15;
    const bool hiT = (p & 2) != 0;
    const int ciA = (p & 1) * 8;
    const int pxA = ml >> 2;
    const int ncA = ml & 3;
    const int bfbase = (oh * 64 + ml) * 32 + p * 8;

    f32x4 acc[4][4];
#pragma unroll
    for (int a = 0; a < 4; ++a)
#pragma unroll
        for (int bb = 0; bb < 4; ++bb)
            acc[a][bb] = (f32x4){0.f, 0.f, 0.f, 0.f};

#pragma unroll
    for (int kk = 0; kk < 13; ++kk) {
        f16x8 bf[4];
#pragma unroll
        for (int bb = 0; bb < 4; ++bb)
            bf[bb] = *(const f16x8*)&wsf[kk * 4096 + bb * 512 + bfbase];

        const int t0 = 2 * kk;
        const int t1 = (2 * kk + 1 > 24) ? 24 : 2 * kk + 1;
        const int dy = hiT ? (t1 / 5) : (t0 / 5);
        const int dx = hiT ? (t1 % 5) : (t0 % 5);

        f16x8 af[4];
#pragma unroll
        for (int a = 0; a < 4; ++a)
            af[a] = *(const f16x8*)&sm[xs_addr6(rwc + dy, a * 4 + pxA + dx, ncA * 16 + ciA)];

#pragma unroll
        for (int a = 0; a < 4; ++a)
#pragma unroll
            for (int bb = 0; bb < 4; ++bb)
                acc[a][bb] = __builtin_amdgcn_mfma_f32_16x16x32_f16(
                    af[a], bf[bb], acc[a][bb], 0, 0, 0);
    }
    __syncthreads();

#pragma unroll
    for (int a = 0; a < 4; ++a) {
#pragma unroll
        for (int reg = 0; reg < 4; ++reg) {
            f16x4 pk;
#pragma unroll
            for (int bb = 0; bb < 4; ++bb) pk[bb] = (_Float16)acc[a][bb][reg];
            const int R = rwc * 64 + a * 16 + p * 4 + reg;
            *(f16x4*)&sm[R * VROW + ml * 8 + oh * 4] = pk;
        }
    }
    __syncthreads();

    const int ncR = tid & 3;
    const int h   = (tid >> 2) & 1;
    const int pxx = (tid >> 3) & 15;
    const int rw  = tid >> 7;

    const int R = rw * 64 + pxx * 4 + ncR;
    f16x8 vh[8];
#pragma unroll
    for (int c8 = 0; c8 < 8; ++c8)
        vh[c8] = *(const f16x8*)&sm[R * VROW + (h * 8 + c8) * 8];

    float* outb = out + (size_t)b * OCH * HWSZ
                + (size_t)(hrow0 + rw) * WW + (w0 + pxx);

    float sims[NPAR];
#pragma unroll
    for (int i = 0; i < NPAR; ++i) sims[i] = 0.f;

#pragma unroll
    for (int it = 0; it < 3; ++it) {
        float mx = fmaxf(fmaxf(fmaxf(sims[0], sims[1]), fmaxf(sims[2], sims[3])),
                         fmaxf(fmaxf(sims[4], sims[5]), fmaxf(sims[6], sims[7])));
        float e[NPAR];
        float se = 0.f;
#pragma unroll
        for (int i = 0; i < NPAR; ++i) { e[i] = __expf(sims[i] - mx); se += e[i]; }
        const float inv = 1.f / se;

#pragma unroll
        for (int np_ = 0; np_ < NPAR; ++np_) {
            const float cf = e[np_] * inv;
            const f16x2 cp = (f16x2){(_Float16)cf, (_Float16)cf};
            float n2 = 0.f, dot = 0.f;
            f16x2 keep0 = (f16x2){(_Float16)0.f, (_Float16)0.f};
            f16x2 keep1 = keep0;
#pragma unroll
            for (int k = 0; k < 4; ++k) {
                const f16x2 vv = (f16x2){vh[2 * k][np_], vh[2 * k + 1][np_]};
                const f16x2 t2 = quad_sum4_pk(cp * vv);
                n2  = fdot2_acc(t2, t2, n2);
                dot = fdot2_acc(vv, t2, dot);
                if (it == 2 && (k >> 1) == (ncR & 1)) {
                    if (k & 1) keep1 = t2; else keep0 = t2;
                }
            }
            n2  += __shfl_xor(n2, 4);
            dot += __shfl_xor(dot, 4);
            const float scale = sqrtf(n2) / (1.f + n2 + 1e-4f);
            sims[np_] += scale * dot;

            if (it == 2 && (ncR >> 1) == h) {
                outb[(size_t)(np_ * LPAR + ncR * 4 + 0) * HWSZ] = scale * (float)keep0[0];
                outb[(size_t)(np_ * LPAR + ncR * 4 + 1) * HWSZ] = scale * (float)keep0[1];
                outb[(size_t)(np_ * LPAR + ncR * 4 + 2) * HWSZ] = scale * (float)keep1[0];
                outb[(size_t)(np_ * LPAR + ncR * 4 + 3) * HWSZ] = scale * (float)keep1[1];
            }
        }
    }
}

extern "C" void kernel_launch(void* const* d_in, const int* in_sizes, int n_in,
                              void* d_out, int out_size, void* d_ws, size_t ws_size,
                              hipStream_t stream) {
    const float* x  = (const float*)d_in[0];   // (4,4,16,256,256) f32
    const float* Wg = (const float*)d_in[1];   // (128,16,5,5) f32
    float* out = (float*)d_out;                // (4,8,16,256,256) f32
    _Float16* ws = (_Float16*)d_ws;
    (void)in_sizes; (void)n_in; (void)out_size;

    const size_t XH_BYTES = (size_t)4 * 260 * 260 * 64 * 2;   // 34,611,200
    const size_t NEED = 131072 + XH_BYTES;

    hipLaunchKernelGGL(reorder_W_lin, dim3(208), dim3(256), 0, stream, Wg, ws);

    if (ws_size >= NEED) {
        _Float16* xh = ws + 65536;   // byte offset 131072
        hipMemsetAsync((void*)xh, 0, XH_BYTES, stream);
        hipLaunchKernelGGL(transpose_x_kernel, dim3(4096), dim3(256), 0, stream, x, xh);
        hipLaunchKernelGGL(capsule_mfma10_kernel, dim3(8192), dim3(256), 0, stream,
                           xh, ws, out);
    } else {
        hipLaunchKernelGGL(capsule_mfma6_kernel, dim3(8192), dim3(256), 0, stream,
                           x, ws, out);
    }
}